// Round 8
// baseline (250.424 us; speedup 1.0000x reference)
//
#include <hip/hip_runtime.h>
#include <hip/hip_bf16.h>

#define NBATCH 16
#define NBR    8
#define CIN    3
#define HIN    224
#define WIN    224
#define COUT   64
#define OHH    112
#define OWW    112
#define PHH    56
#define PWW    56
#define CNT    (NBATCH*OHH*OWW)                  // 200704 per (b,co) channel
#define YSLOT  ((size_t)NBATCH*OHH*OWW*COUT)     // y elements per branch

// padded x: per image [4 ci][230 h][232 w] bf16 (zeros baked in; ci=3 plane all-zero)
#define XCI  4
#define XH   230
#define XW   232
#define XIMG ((size_t)XCI*XH*XW)                 // 213440 elems per image
#define BROW 200                                 // wt row stride in ushorts (192 + 8 pad)

typedef __bf16 bf16x8 __attribute__((ext_vector_type(8)));
typedef float  f32x4  __attribute__((ext_vector_type(4)));
typedef unsigned int uint4v __attribute__((ext_vector_type(4)));
typedef unsigned int uint2v __attribute__((ext_vector_type(2)));

// ---------- wt[b][co][k'] bf16: k' = g*8+j, g=(ci*7+kh), j=kw (j=7 or g>=21 -> 0) ----------
__global__ __launch_bounds__(256)
void prep_w(const float* __restrict__ w, ushort* __restrict__ wt)
{
    int i = blockIdx.x*256 + threadIdx.x;
    if (i >= NBR*COUT*BROW) return;
    int k = i % BROW;
    int t = i / BROW;                       // b*64 + co
    float v = 0.f;
    if (k < 168) {
        int g = k >> 3, j = k & 7;
        if (j < 7) {
            int ci = g / 7, kh = g - 7*ci;
            v = w[(size_t)t*147 + ci*49 + kh*7 + j];
        }
    }
    __hip_bfloat16 h = __float2bfloat16(v);
    wt[i] = *reinterpret_cast<ushort*>(&h);
}

// ---------- padded bf16 x. interior only (memset provides zeros elsewhere) ----------
__global__ __launch_bounds__(256)
void prep_x(const float* __restrict__ x, ushort* __restrict__ xp)
{
    int bid = blockIdx.x;
    int hc  = bid % 14;
    int t2  = bid / 14;
    int ci  = t2 % 3;
    int img = t2 / 3;
    const float* src = x + ((size_t)img*3 + ci)*HIN*WIN;
    ushort* dst = xp + (size_t)img*XIMG + (size_t)ci*XH*XW;
    for (int i = threadIdx.x; i < 16*224; i += 256) {
        int hh = hc*16 + (i / 224);
        int c  = i % 224;
        float v = src[hh*WIN + c];
        __hip_bfloat16 h = __float2bfloat16(v);
        dst[(hh+3)*XW + (c+3)] = *reinterpret_cast<ushort*>(&h);
    }
}

// ---------- MFMA conv, swapped operands: D[row=co][col=px] ----------
// A = w frag (row=co, k), B = x frag (k, col=px). Lane (l15,q) holds, per nt:
// px = pxb + l15, co = nt*16 + q*4 + r (r=0..3) -> 4 consecutive co = uint2 store.
__global__ __launch_bounds__(256)
void conv_mfma(const ushort* __restrict__ xp, const ushort* __restrict__ wt,
               ushort* __restrict__ y, float* __restrict__ stats, int bbase)
{
    __shared__ float red[4][2][COUT];    // 2 KB

    int bloc = blockIdx.x / 224;
    int tb   = (blockIdx.x % 224) * 14;
    int b    = bbase + bloc;
    int tid  = threadIdx.x;
    int wid  = tid >> 6;
    int lane = tid & 63;
    int l15  = lane & 15;
    int q    = lane >> 4;

    // B-frags of W direct from global (L2-hot): w[co=nt*16+l15][k=ks*32+q*8+j]
    uint4v bfr[4][6];
    #pragma unroll
    for (int nt = 0; nt < 4; ++nt)
        #pragma unroll
        for (int ks = 0; ks < 6; ++ks)
            bfr[nt][ks] = *(const uint4v*)&wt[((size_t)b*COUT + nt*16 + l15)*BROW
                                              + ks*32 + q*8];

    int goff[6];
    #pragma unroll
    for (int ks = 0; ks < 6; ++ks) {
        int g = ks*4 + q;
        int ci = g / 7, kh = g - 7*ci;
        goff[ks] = (ci*XH + kh) * (XW*2);
    }

    float ss[4][4], sq[4][4];
    #pragma unroll
    for (int nt = 0; nt < 4; ++nt)
        #pragma unroll
        for (int r = 0; r < 4; ++r) { ss[nt][r] = 0.f; sq[nt][r] = 0.f; }

    ushort* ybb = y + (size_t)bloc*YSLOT;

    #pragma unroll 1
    for (int t = 0; t < 14; ++t) {
        int pxb = (tb + t)*64 + wid*16;
        int p   = pxb + l15;
        int n   = p / (OHH*OWW);
        int r1  = p - n*(OHH*OWW);
        int oh  = r1 / OWW;
        int ow  = r1 - oh*OWW;
        int img = n*NBR + b;
        const char* abase = (const char*)xp + (size_t)img*(XIMG*2)
                          + (size_t)(2*oh)*(XW*2) + (size_t)(4*ow);

        uint4v afr[6];
        #pragma unroll
        for (int ks = 0; ks < 6; ++ks)
            __builtin_memcpy(&afr[ks], abase + goff[ks], 16);

        f32x4 acc[4];
        #pragma unroll
        for (int nt = 0; nt < 4; ++nt) acc[nt] = (f32x4){0.f,0.f,0.f,0.f};

        #pragma unroll
        for (int ks = 0; ks < 6; ++ks)
            #pragma unroll
            for (int nt = 0; nt < 4; ++nt)
                acc[nt] = __builtin_amdgcn_mfma_f32_16x16x32_bf16(
                    __builtin_bit_cast(bf16x8, bfr[nt][ks]),   // A = w
                    __builtin_bit_cast(bf16x8, afr[ks]),       // B = x
                    acc[nt], 0, 0, 0);

        ushort* yrow = ybb + (size_t)(pxb + l15)*64 + q*4;
        #pragma unroll
        for (int nt = 0; nt < 4; ++nt) {
            float v0 = acc[nt][0], v1 = acc[nt][1], v2 = acc[nt][2], v3 = acc[nt][3];
            ss[nt][0] += v0; sq[nt][0] += v0*v0;
            ss[nt][1] += v1; sq[nt][1] += v1*v1;
            ss[nt][2] += v2; sq[nt][2] += v2*v2;
            ss[nt][3] += v3; sq[nt][3] += v3*v3;
            __hip_bfloat16 h0 = __float2bfloat16(v0);
            __hip_bfloat16 h1 = __float2bfloat16(v1);
            __hip_bfloat16 h2 = __float2bfloat16(v2);
            __hip_bfloat16 h3 = __float2bfloat16(v3);
            uint2v pk;
            pk[0] = (uint)*reinterpret_cast<ushort*>(&h0)
                  | ((uint)*reinterpret_cast<ushort*>(&h1) << 16);
            pk[1] = (uint)*reinterpret_cast<ushort*>(&h2)
                  | ((uint)*reinterpret_cast<ushort*>(&h3) << 16);
            *(uint2v*)(yrow + nt*16) = pk;
        }
    }

    // reduce ss/sq over l15 (px) within each q-group: co = nt*16 + q*4 + r
    #pragma unroll
    for (int nt = 0; nt < 4; ++nt)
        #pragma unroll
        for (int r = 0; r < 4; ++r) {
            float s = ss[nt][r], z = sq[nt][r];
            #pragma unroll
            for (int off = 1; off < 16; off <<= 1) {
                s += __shfl_xor(s, off);
                z += __shfl_xor(z, off);
            }
            ss[nt][r] = s; sq[nt][r] = z;
        }
    if (l15 == 0) {
        #pragma unroll
        for (int nt = 0; nt < 4; ++nt)
            #pragma unroll
            for (int r = 0; r < 4; ++r) {
                red[wid][0][nt*16 + q*4 + r] = ss[nt][r];
                red[wid][1][nt*16 + q*4 + r] = sq[nt][r];
            }
    }
    __syncthreads();
    if (tid < 64) {
        float s  = red[0][0][tid] + red[1][0][tid] + red[2][0][tid] + red[3][0][tid];
        float qq = red[0][1][tid] + red[1][1][tid] + red[2][1][tid] + red[3][1][tid];
        atomicAdd(&stats[b*128 + tid*2 + 0], s);
        atomicAdd(&stats[b*128 + tid*2 + 1], qq);
    }
}

// ---------- vectorized pool: uint4 reads (8 co / 16 B / lane), clamped windows ----------
__device__ __forceinline__ void upd8(const ushort* __restrict__ p,
                                     float* __restrict__ mx, float* __restrict__ mn)
{
    uint4v v = *(const uint4v*)p;
    #pragma unroll
    for (int i = 0; i < 4; ++i) {
        uint u = v[i];
        float f0 = __builtin_bit_cast(float, u << 16);
        float f1 = __builtin_bit_cast(float, u & 0xffff0000u);
        mx[2*i]   = fmaxf(mx[2*i],   f0);  mn[2*i]   = fminf(mn[2*i],   f0);
        mx[2*i+1] = fmaxf(mx[2*i+1], f1);  mn[2*i+1] = fminf(mn[2*i+1], f1);
    }
}

// block = one (bloc,n,ph) output row; thread = (pw-group, co-octet).
__global__ __launch_bounds__(256)
void pool_fast(const ushort* __restrict__ y, const float* __restrict__ stats,
               const float* __restrict__ gamma, const float* __restrict__ beta,
               float* __restrict__ out, int bbase)
{
    int bid  = blockIdx.x;
    int bloc = bid / (NBATCH*PHH);
    int r    = bid % (NBATCH*PHH);
    int n    = r / PHH;
    int ph   = r % PHH;
    int b    = bbase + bloc;
    int tid  = threadIdx.x;

    __shared__ float res[PWW][COUT+1];       // 14.6 KB
    __shared__ float sscale[COUT], sshift[COUT];

    if (tid < COUT) {
        float mean = stats[b*128 + tid*2 + 0] * (1.f/CNT);
        float var  = stats[b*128 + tid*2 + 1] * (1.f/CNT) - mean*mean;
        float inv  = rsqrtf(var + 1e-5f);
        float sc   = gamma[b*COUT + tid]*inv;
        sscale[tid] = sc;
        sshift[tid] = beta[b*COUT + tid] - mean*sc;
    }
    __syncthreads();

    const ushort* yb = y + (size_t)bloc*YSLOT + (size_t)n*OHH*OWW*64;
    int c8 = (tid & 7) * 8;      // co octet base
    int pg = tid >> 3;           // 0..31

    int ihA = (2*ph-1 < 0) ? 0 : 2*ph-1;
    int ihB = 2*ph;
    int ihC = (2*ph+1 > OHH-1) ? OHH-1 : 2*ph+1;
    const ushort* rA = yb + (size_t)ihA*OWW*64;
    const ushort* rB = yb + (size_t)ihB*OWW*64;
    const ushort* rC = yb + (size_t)ihC*OWW*64;

    #pragma unroll
    for (int t = 0; t < 2; ++t) {
        int pw = pg + 32*t;
        if (pw < PWW) {
            int iwL = (2*pw-1 < 0) ? 0 : 2*pw-1;
            int iwC = 2*pw;
            int iwR = (2*pw+1 > OWW-1) ? OWW-1 : 2*pw+1;
            int oL = iwL*64 + c8, oC = iwC*64 + c8, oR = iwR*64 + c8;

            float mx[8], mn[8];
            #pragma unroll
            for (int j = 0; j < 8; ++j) { mx[j] = -1e30f; mn[j] = 1e30f; }
            upd8(rA + oL, mx, mn); upd8(rA + oC, mx, mn); upd8(rA + oR, mx, mn);
            upd8(rB + oL, mx, mn); upd8(rB + oC, mx, mn); upd8(rB + oR, mx, mn);
            upd8(rC + oL, mx, mn); upd8(rC + oC, mx, mn); upd8(rC + oR, mx, mn);

            #pragma unroll
            for (int j = 0; j < 8; ++j) {
                int co = c8 + j;
                float sc = sscale[co];
                float v  = (sc >= 0.f) ? mx[j] : mn[j];   // affine+relu monotone
                res[pw][co] = fmaxf(fmaf(v, sc, sshift[co]), 0.f);
            }
        }
    }
    __syncthreads();

    float* ob = out + (((size_t)n*NBR + b)*COUT)*(PHH*PWW) + (size_t)ph*PWW;
    for (int j = tid; j < COUT*PWW; j += 256) {
        int co = j / PWW;
        int pw = j - co*PWW;
        ob[(size_t)co*(PHH*PWW) + pw] = res[pw][co];
    }
}

// ================= fallback path (tiny workspace) =================
__global__ __launch_bounds__(512)
void conv_bn_stats(const float* __restrict__ x, const float* __restrict__ w,
                   float* __restrict__ stats, int b)
{
    __shared__ float xs[CIN][7][232];
    int bid = blockIdx.x;
    int oh  = bid % OHH;
    int n   = bid / OHH;
    const float* xb = x + ((size_t)(n*NBR + b))*CIN*HIN*WIN;
    int ihb = oh*2 - 3;
    for (int idx = threadIdx.x; idx < CIN*7*230; idx += 512) {
        int ci = idx / (7*230);
        int rr = idx - ci*(7*230);
        int kh = rr / 230;
        int c  = rr - kh*230;
        int ih = ihb + kh, iw = c - 3;
        float v = 0.f;
        if ((unsigned)ih < (unsigned)HIN && (unsigned)iw < (unsigned)WIN)
            v = xb[(ci*HIN + ih)*WIN + iw];
        xs[ci][kh][c] = v;
    }
    __syncthreads();
    int wid  = __builtin_amdgcn_readfirstlane(threadIdx.x >> 6);
    int lane = threadIdx.x & 63;
    int co0  = wid * 8;
    const float* wb = w + ((size_t)b*COUT + co0)*147;
    float acc0[8], acc1[8];
    #pragma unroll
    for (int cc = 0; cc < 8; ++cc) { acc0[cc] = 0.f; acc1[cc] = 0.f; }
    int ow1 = lane + 64;
    for (int ci = 0; ci < CIN; ++ci)
        for (int kh = 0; kh < 7; ++kh) {
            float wr[8][7];
            #pragma unroll
            for (int cc = 0; cc < 8; ++cc)
                #pragma unroll
                for (int kw = 0; kw < 7; ++kw)
                    wr[cc][kw] = wb[cc*147 + ci*49 + kh*7 + kw];
            const float* xr = &xs[ci][kh][0];
            #pragma unroll
            for (int kw = 0; kw < 7; ++kw) {
                float xv0 = xr[lane*2 + kw];
                float xv1 = (ow1 < OWW) ? xr[ow1*2 + kw] : 0.f;
                #pragma unroll
                for (int cc = 0; cc < 8; ++cc) {
                    acc0[cc] = fmaf(xv0, wr[cc][kw], acc0[cc]);
                    acc1[cc] = fmaf(xv1, wr[cc][kw], acc1[cc]);
                }
            }
        }
    #pragma unroll
    for (int cc = 0; cc < 8; ++cc) {
        float s = acc0[cc] + acc1[cc];
        float qv = acc0[cc]*acc0[cc] + acc1[cc]*acc1[cc];
        #pragma unroll
        for (int off = 32; off; off >>= 1) {
            s  += __shfl_xor(s, off);
            qv += __shfl_xor(qv, off);
        }
        if (lane == 0) {
            atomicAdd(&stats[(co0+cc)*2 + 0], s);
            atomicAdd(&stats[(co0+cc)*2 + 1], qv);
        }
    }
}

__global__ __launch_bounds__(256)
void pool_recompute(const float* __restrict__ x, const float* __restrict__ w,
                    const float* __restrict__ stats, const float* __restrict__ gamma,
                    const float* __restrict__ beta, float* __restrict__ out, int b)
{
    int idx = blockIdx.x*256 + threadIdx.x;
    int pw = idx % PWW;
    int t  = idx / PWW;
    int ph = t % PHH; t /= PHH;
    int co = t % COUT;
    int n  = t / COUT;
    float mean = stats[co*2 + 0] * (1.f/CNT);
    float var  = stats[co*2 + 1] * (1.f/CNT) - mean*mean;
    float inv  = rsqrtf(var + 1e-5f);
    float scale = gamma[co]*inv;
    float shift = beta[co] - mean*scale;
    const float* xb = x + ((size_t)(n*NBR + b))*CIN*HIN*WIN;
    const float* wb = w + ((size_t)b*COUT + co)*147;
    float mx = -1e30f, mn = 1e30f;
    for (int dh = 0; dh < 3; ++dh) {
        int oh = 2*ph - 1 + dh;
        if ((unsigned)oh >= (unsigned)OHH) continue;
        for (int dw = 0; dw < 3; ++dw) {
            int ow = 2*pw - 1 + dw;
            if ((unsigned)ow >= (unsigned)OWW) continue;
            float a = 0.f;
            for (int ci = 0; ci < CIN; ++ci)
                for (int kh = 0; kh < 7; ++kh) {
                    int ih = oh*2 - 3 + kh;
                    if ((unsigned)ih >= (unsigned)HIN) continue;
                    for (int kw = 0; kw < 7; ++kw) {
                        int iw = ow*2 - 3 + kw;
                        if ((unsigned)iw >= (unsigned)WIN) continue;
                        a = fmaf(xb[(ci*HIN + ih)*WIN + iw], wb[ci*49 + kh*7 + kw], a);
                    }
                }
            mx = fmaxf(mx, a);
            mn = fminf(mn, a);
        }
    }
    float v = (scale >= 0.f) ? mx : mn;
    out[(((size_t)n*NBR + b)*COUT + co)*(PHH*PWW) + (size_t)ph*PWW + pw] =
        fmaxf(fmaf(v, scale, shift), 0.f);
}

extern "C" void kernel_launch(void* const* d_in, const int* in_sizes, int n_in,
                              void* d_out, int out_size, void* d_ws, size_t ws_size,
                              hipStream_t stream) {
    const float* x     = (const float*)d_in[0];
    const float* w     = (const float*)d_in[1];
    const float* gamma = (const float*)d_in[2];
    const float* beta  = (const float*)d_in[3];
    float* out = (float*)d_out;

    // ws: [0,4K) stats; [4K,~209K) wt (8x64x200 bf16); [256K, +54.6MB) xpad; then y slots
    float*  stats = (float*)d_ws;
    ushort* wt    = (ushort*)((char*)d_ws + 4096);
    ushort* xp    = (ushort*)((char*)d_ws + 262144);
    const size_t ybase  = 262144 + (size_t)128*XIMG*2;   // ~54.9 MB
    const size_t yBytes = YSLOT*2;                       // 25.69 MB per branch
    ushort* y = (ushort*)((char*)d_ws + ybase);

    int ng = 0;
    if (ws_size > ybase + yBytes)
        ng = (int)((ws_size - ybase) / yBytes);
    if (ng > NBR) ng = NBR;

    if (ng >= 1) {
        hipMemsetAsync(d_ws, 0, ybase, stream);   // zeros stats + wt pad + xpad padding
        prep_w<<<(NBR*COUT*BROW + 255)/256, 256, 0, stream>>>(w, wt);
        prep_x<<<128*3*14, 256, 0, stream>>>(x, xp);
        for (int g = 0; g < NBR; g += ng) {
            int nb = (NBR - g < ng) ? (NBR - g) : ng;
            conv_mfma<<<nb*224, 256, 0, stream>>>(xp, wt, y, stats, g);
            pool_fast<<<nb*NBATCH*PHH, 256, 0, stream>>>(y, stats, gamma, beta, out, g);
        }
    } else {
        hipMemsetAsync(d_ws, 0, NBR*128*sizeof(float), stream);
        for (int b = 0; b < NBR; ++b) {
            float* statsB = stats + b*128;
            conv_bn_stats<<<NBATCH*OHH, 512, 0, stream>>>(x, w, statsB, b);
            pool_recompute<<<NBATCH*COUT*PHH*PWW/256, 256, 0, stream>>>(
                x, w, statsB, gamma + b*COUT, beta + b*COUT, out, b);
        }
    }
}

// Round 9
// 227.149 us; speedup vs baseline: 1.1025x; 1.1025x over previous
//
#include <hip/hip_runtime.h>
#include <hip/hip_bf16.h>

#define NBATCH 16
#define NBR    8
#define CIN    3
#define HIN    224
#define WIN    224
#define COUT   64
#define OHH    112
#define OWW    112
#define PHH    56
#define PWW    56
#define CNT    (NBATCH*OHH*OWW)                  // 200704 per (b,co) channel
#define YSLOT  ((size_t)NBATCH*OHH*OWW*COUT)     // y elements per branch

// padded x: per image [4 ci][230 h][232 w] bf16 (zeros baked in; ci=3 plane all-zero)
#define XCI  4
#define XH   230
#define XW   232
#define XIMG ((size_t)XCI*XH*XW)                 // 213440 elems per image
#define BROW 200                                 // wt row stride in ushorts (192 + 8 pad)

typedef __bf16 bf16x8 __attribute__((ext_vector_type(8)));
typedef float  f32x4  __attribute__((ext_vector_type(4)));
typedef unsigned int uint4v __attribute__((ext_vector_type(4)));
typedef unsigned int uint2v __attribute__((ext_vector_type(2)));

// ---------- wt[b][co][k'] bf16: k' = g*8+j, g=(ci*7+kh), j=kw (j=7 or g>=21 -> 0) ----------
__global__ __launch_bounds__(256)
void prep_w(const float* __restrict__ w, ushort* __restrict__ wt)
{
    int i = blockIdx.x*256 + threadIdx.x;
    if (i >= NBR*COUT*BROW) return;
    int k = i % BROW;
    int t = i / BROW;                       // b*64 + co
    float v = 0.f;
    if (k < 168) {
        int g = k >> 3, j = k & 7;
        if (j < 7) {
            int ci = g / 7, kh = g - 7*ci;
            v = w[(size_t)t*147 + ci*49 + kh*7 + j];
        }
    }
    __hip_bfloat16 h = __float2bfloat16(v);
    wt[i] = *reinterpret_cast<ushort*>(&h);
}

// ---------- padded bf16 x. interior only (memset provides zeros elsewhere) ----------
__global__ __launch_bounds__(256)
void prep_x(const float* __restrict__ x, ushort* __restrict__ xp)
{
    int bid = blockIdx.x;
    int hc  = bid % 14;
    int t2  = bid / 14;
    int ci  = t2 % 3;
    int img = t2 / 3;
    const float* src = x + ((size_t)img*3 + ci)*HIN*WIN;
    ushort* dst = xp + (size_t)img*XIMG + (size_t)ci*XH*XW;
    for (int i = threadIdx.x; i < 16*224; i += 256) {
        int hh = hc*16 + (i / 224);
        int c  = i % 224;
        float v = src[hh*WIN + c];
        __hip_bfloat16 h = __float2bfloat16(v);
        dst[(hh+3)*XW + (c+3)] = *reinterpret_cast<ushort*>(&h);
    }
}

// ---------- MFMA conv: LDS-staged W frags (r7) + swapped operands (r8) + afr prefetch ----------
// D[row=co][col=px]: lane (l15,q) holds px=pxb+l15, co=nt*16+q*4+r -> packed uint2 stores.
__global__ __launch_bounds__(256)
void conv_mfma(const ushort* __restrict__ xp, const ushort* __restrict__ wt,
               ushort* __restrict__ y, float* __restrict__ stats, int bbase)
{
    __shared__ ushort bt[COUT*BROW];     // 25.6 KB
    __shared__ float red[4][2][COUT];    // 2 KB

    int bloc = blockIdx.x / 224;
    int tb   = (blockIdx.x % 224) * 14;
    int b    = bbase + bloc;
    int tid  = threadIdx.x;
    int wid  = tid >> 6;
    int lane = tid & 63;
    int l15  = lane & 15;
    int q    = lane >> 4;

    {   // stage wt row-block into LDS (coalesced dword copy)
        const uint* s = (const uint*)(wt + (size_t)b*COUT*BROW);
        uint* d = (uint*)bt;
        for (int i = tid; i < COUT*BROW/2; i += 256) d[i] = s[i];
    }
    __syncthreads();

    // W frags from LDS: A-operand rows = co. w[co=nt*16+l15][k=ks*32+q*8+j]
    uint4v bfr[4][6];
    #pragma unroll
    for (int nt = 0; nt < 4; ++nt)
        #pragma unroll
        for (int ks = 0; ks < 6; ++ks)
            bfr[nt][ks] = *(const uint4v*)&bt[(nt*16 + l15)*BROW + ks*32 + q*8];

    int goff[6];
    #pragma unroll
    for (int ks = 0; ks < 6; ++ks) {
        int g = ks*4 + q;
        int ci = g / 7, kh = g - 7*ci;
        goff[ks] = (ci*XH + kh) * (XW*2);
    }

    float ss[4][4], sq[4][4];
    #pragma unroll
    for (int nt = 0; nt < 4; ++nt)
        #pragma unroll
        for (int r = 0; r < 4; ++r) { ss[nt][r] = 0.f; sq[nt][r] = 0.f; }

    ushort* ybb = y + (size_t)bloc*YSLOT;

    auto abase_of = [&](int t) -> const char* {
        int p  = (tb + t)*64 + wid*16 + l15;
        int n  = p / (OHH*OWW);
        int r1 = p - n*(OHH*OWW);
        int oh = r1 / OWW;
        int ow = r1 - oh*OWW;
        int img = n*NBR + b;
        return (const char*)xp + (size_t)img*(XIMG*2)
             + (size_t)(2*oh)*(XW*2) + (size_t)(4*ow);
    };

    uint4v afrA[6], afrB[6];
    {
        const char* a0 = abase_of(0);
        #pragma unroll
        for (int ks = 0; ks < 6; ++ks)
            __builtin_memcpy(&afrA[ks], a0 + goff[ks], 16);
    }

    #pragma unroll 1
    for (int t = 0; t < 14; ++t) {
        // prefetch next tile's A frags (hidden under this tile's MFMA+epilogue)
        if (t < 13) {
            const char* a1 = abase_of(t + 1);
            #pragma unroll
            for (int ks = 0; ks < 6; ++ks)
                __builtin_memcpy(&afrB[ks], a1 + goff[ks], 16);
        }

        f32x4 acc[4];
        #pragma unroll
        for (int nt = 0; nt < 4; ++nt) acc[nt] = (f32x4){0.f,0.f,0.f,0.f};

        #pragma unroll
        for (int ks = 0; ks < 6; ++ks)
            #pragma unroll
            for (int nt = 0; nt < 4; ++nt)
                acc[nt] = __builtin_amdgcn_mfma_f32_16x16x32_bf16(
                    __builtin_bit_cast(bf16x8, bfr[nt][ks]),   // A = w (rows=co)
                    __builtin_bit_cast(bf16x8, afrA[ks]),      // B = x (cols=px)
                    acc[nt], 0, 0, 0);

        int pxb = (tb + t)*64 + wid*16;
        ushort* yrow = ybb + (size_t)(pxb + l15)*64 + q*4;
        #pragma unroll
        for (int nt = 0; nt < 4; ++nt) {
            float v0 = acc[nt][0], v1 = acc[nt][1], v2 = acc[nt][2], v3 = acc[nt][3];
            ss[nt][0] += v0; sq[nt][0] += v0*v0;
            ss[nt][1] += v1; sq[nt][1] += v1*v1;
            ss[nt][2] += v2; sq[nt][2] += v2*v2;
            ss[nt][3] += v3; sq[nt][3] += v3*v3;
            __hip_bfloat16 h0 = __float2bfloat16(v0);
            __hip_bfloat16 h1 = __float2bfloat16(v1);
            __hip_bfloat16 h2 = __float2bfloat16(v2);
            __hip_bfloat16 h3 = __float2bfloat16(v3);
            uint2v pk;
            pk[0] = (uint)*reinterpret_cast<ushort*>(&h0)
                  | ((uint)*reinterpret_cast<ushort*>(&h1) << 16);
            pk[1] = (uint)*reinterpret_cast<ushort*>(&h2)
                  | ((uint)*reinterpret_cast<ushort*>(&h3) << 16);
            *(uint2v*)(yrow + nt*16) = pk;
        }

        #pragma unroll
        for (int ks = 0; ks < 6; ++ks) afrA[ks] = afrB[ks];
    }

    // stats: reduce over l15 (px), co = nt*16 + q*4 + r
    #pragma unroll
    for (int nt = 0; nt < 4; ++nt)
        #pragma unroll
        for (int r = 0; r < 4; ++r) {
            float s = ss[nt][r], z = sq[nt][r];
            #pragma unroll
            for (int off = 1; off < 16; off <<= 1) {
                s += __shfl_xor(s, off);
                z += __shfl_xor(z, off);
            }
            ss[nt][r] = s; sq[nt][r] = z;
        }
    if (l15 == 0) {
        #pragma unroll
        for (int nt = 0; nt < 4; ++nt)
            #pragma unroll
            for (int r = 0; r < 4; ++r) {
                red[wid][0][nt*16 + q*4 + r] = ss[nt][r];
                red[wid][1][nt*16 + q*4 + r] = sq[nt][r];
            }
    }
    __syncthreads();
    if (tid < 64) {
        float s  = red[0][0][tid] + red[1][0][tid] + red[2][0][tid] + red[3][0][tid];
        float qq = red[0][1][tid] + red[1][1][tid] + red[2][1][tid] + red[3][1][tid];
        atomicAdd(&stats[b*128 + tid*2 + 0], s);
        atomicAdd(&stats[b*128 + tid*2 + 1], qq);
    }
}

// ---------- vectorized pool: uint4 reads (8 co / 16 B / lane), clamped windows ----------
__device__ __forceinline__ void upd8(const ushort* __restrict__ p,
                                     float* __restrict__ mx, float* __restrict__ mn)
{
    uint4v v = *(const uint4v*)p;
    #pragma unroll
    for (int i = 0; i < 4; ++i) {
        uint u = v[i];
        float f0 = __builtin_bit_cast(float, u << 16);
        float f1 = __builtin_bit_cast(float, u & 0xffff0000u);
        mx[2*i]   = fmaxf(mx[2*i],   f0);  mn[2*i]   = fminf(mn[2*i],   f0);
        mx[2*i+1] = fmaxf(mx[2*i+1], f1);  mn[2*i+1] = fminf(mn[2*i+1], f1);
    }
}

// block = one (bloc,n,ph) output row; thread = (pw-group, co-octet).
__global__ __launch_bounds__(256)
void pool_fast(const ushort* __restrict__ y, const float* __restrict__ stats,
               const float* __restrict__ gamma, const float* __restrict__ beta,
               float* __restrict__ out, int bbase)
{
    int bid  = blockIdx.x;
    int bloc = bid / (NBATCH*PHH);
    int r    = bid % (NBATCH*PHH);
    int n    = r / PHH;
    int ph   = r % PHH;
    int b    = bbase + bloc;
    int tid  = threadIdx.x;

    __shared__ float res[PWW][COUT+1];       // 14.6 KB
    __shared__ float sscale[COUT], sshift[COUT];

    if (tid < COUT) {
        float mean = stats[b*128 + tid*2 + 0] * (1.f/CNT);
        float var  = stats[b*128 + tid*2 + 1] * (1.f/CNT) - mean*mean;
        float inv  = rsqrtf(var + 1e-5f);
        float sc   = gamma[b*COUT + tid]*inv;
        sscale[tid] = sc;
        sshift[tid] = beta[b*COUT + tid] - mean*sc;
    }
    __syncthreads();

    const ushort* yb = y + (size_t)bloc*YSLOT + (size_t)n*OHH*OWW*64;
    int c8 = (tid & 7) * 8;      // co octet base
    int pg = tid >> 3;           // 0..31

    int ihA = (2*ph-1 < 0) ? 0 : 2*ph-1;
    int ihB = 2*ph;
    int ihC = (2*ph+1 > OHH-1) ? OHH-1 : 2*ph+1;
    const ushort* rA = yb + (size_t)ihA*OWW*64;
    const ushort* rB = yb + (size_t)ihB*OWW*64;
    const ushort* rC = yb + (size_t)ihC*OWW*64;

    #pragma unroll
    for (int t = 0; t < 2; ++t) {
        int pw = pg + 32*t;
        if (pw < PWW) {
            int iwL = (2*pw-1 < 0) ? 0 : 2*pw-1;
            int iwC = 2*pw;
            int iwR = (2*pw+1 > OWW-1) ? OWW-1 : 2*pw+1;
            int oL = iwL*64 + c8, oC = iwC*64 + c8, oR = iwR*64 + c8;

            float mx[8], mn[8];
            #pragma unroll
            for (int j = 0; j < 8; ++j) { mx[j] = -1e30f; mn[j] = 1e30f; }
            upd8(rA + oL, mx, mn); upd8(rA + oC, mx, mn); upd8(rA + oR, mx, mn);
            upd8(rB + oL, mx, mn); upd8(rB + oC, mx, mn); upd8(rB + oR, mx, mn);
            upd8(rC + oL, mx, mn); upd8(rC + oC, mx, mn); upd8(rC + oR, mx, mn);

            #pragma unroll
            for (int j = 0; j < 8; ++j) {
                int co = c8 + j;
                float sc = sscale[co];
                float v  = (sc >= 0.f) ? mx[j] : mn[j];   // affine+relu monotone
                res[pw][co] = fmaxf(fmaf(v, sc, sshift[co]), 0.f);
            }
        }
    }
    __syncthreads();

    float* ob = out + (((size_t)n*NBR + b)*COUT)*(PHH*PWW) + (size_t)ph*PWW;
    for (int j = tid; j < COUT*PWW; j += 256) {
        int co = j / PWW;
        int pw = j - co*PWW;
        ob[(size_t)co*(PHH*PWW) + pw] = res[pw][co];
    }
}

// ================= fallback path (tiny workspace) =================
__global__ __launch_bounds__(512)
void conv_bn_stats(const float* __restrict__ x, const float* __restrict__ w,
                   float* __restrict__ stats, int b)
{
    __shared__ float xs[CIN][7][232];
    int bid = blockIdx.x;
    int oh  = bid % OHH;
    int n   = bid / OHH;
    const float* xb = x + ((size_t)(n*NBR + b))*CIN*HIN*WIN;
    int ihb = oh*2 - 3;
    for (int idx = threadIdx.x; idx < CIN*7*230; idx += 512) {
        int ci = idx / (7*230);
        int rr = idx - ci*(7*230);
        int kh = rr / 230;
        int c  = rr - kh*230;
        int ih = ihb + kh, iw = c - 3;
        float v = 0.f;
        if ((unsigned)ih < (unsigned)HIN && (unsigned)iw < (unsigned)WIN)
            v = xb[(ci*HIN + ih)*WIN + iw];
        xs[ci][kh][c] = v;
    }
    __syncthreads();
    int wid  = __builtin_amdgcn_readfirstlane(threadIdx.x >> 6);
    int lane = threadIdx.x & 63;
    int co0  = wid * 8;
    const float* wb = w + ((size_t)b*COUT + co0)*147;
    float acc0[8], acc1[8];
    #pragma unroll
    for (int cc = 0; cc < 8; ++cc) { acc0[cc] = 0.f; acc1[cc] = 0.f; }
    int ow1 = lane + 64;
    for (int ci = 0; ci < CIN; ++ci)
        for (int kh = 0; kh < 7; ++kh) {
            float wr[8][7];
            #pragma unroll
            for (int cc = 0; cc < 8; ++cc)
                #pragma unroll
                for (int kw = 0; kw < 7; ++kw)
                    wr[cc][kw] = wb[cc*147 + ci*49 + kh*7 + kw];
            const float* xr = &xs[ci][kh][0];
            #pragma unroll
            for (int kw = 0; kw < 7; ++kw) {
                float xv0 = xr[lane*2 + kw];
                float xv1 = (ow1 < OWW) ? xr[ow1*2 + kw] : 0.f;
                #pragma unroll
                for (int cc = 0; cc < 8; ++cc) {
                    acc0[cc] = fmaf(xv0, wr[cc][kw], acc0[cc]);
                    acc1[cc] = fmaf(xv1, wr[cc][kw], acc1[cc]);
                }
            }
        }
    #pragma unroll
    for (int cc = 0; cc < 8; ++cc) {
        float s = acc0[cc] + acc1[cc];
        float qv = acc0[cc]*acc0[cc] + acc1[cc]*acc1[cc];
        #pragma unroll
        for (int off = 32; off; off >>= 1) {
            s  += __shfl_xor(s, off);
            qv += __shfl_xor(qv, off);
        }
        if (lane == 0) {
            atomicAdd(&stats[(co0+cc)*2 + 0], s);
            atomicAdd(&stats[(co0+cc)*2 + 1], qv);
        }
    }
}

__global__ __launch_bounds__(256)
void pool_recompute(const float* __restrict__ x, const float* __restrict__ w,
                    const float* __restrict__ stats, const float* __restrict__ gamma,
                    const float* __restrict__ beta, float* __restrict__ out, int b)
{
    int idx = blockIdx.x*256 + threadIdx.x;
    int pw = idx % PWW;
    int t  = idx / PWW;
    int ph = t % PHH; t /= PHH;
    int co = t % COUT;
    int n  = t / COUT;
    float mean = stats[co*2 + 0] * (1.f/CNT);
    float var  = stats[co*2 + 1] * (1.f/CNT) - mean*mean;
    float inv  = rsqrtf(var + 1e-5f);
    float scale = gamma[co]*inv;
    float shift = beta[co] - mean*scale;
    const float* xb = x + ((size_t)(n*NBR + b))*CIN*HIN*WIN;
    const float* wb = w + ((size_t)b*COUT + co)*147;
    float mx = -1e30f, mn = 1e30f;
    for (int dh = 0; dh < 3; ++dh) {
        int oh = 2*ph - 1 + dh;
        if ((unsigned)oh >= (unsigned)OHH) continue;
        for (int dw = 0; dw < 3; ++dw) {
            int ow = 2*pw - 1 + dw;
            if ((unsigned)ow >= (unsigned)OWW) continue;
            float a = 0.f;
            for (int ci = 0; ci < CIN; ++ci)
                for (int kh = 0; kh < 7; ++kh) {
                    int ih = oh*2 - 3 + kh;
                    if ((unsigned)ih >= (unsigned)HIN) continue;
                    for (int kw = 0; kw < 7; ++kw) {
                        int iw = ow*2 - 3 + kw;
                        if ((unsigned)iw >= (unsigned)WIN) continue;
                        a = fmaf(xb[(ci*HIN + ih)*WIN + iw], wb[ci*49 + kh*7 + kw], a);
                    }
                }
            mx = fmaxf(mx, a);
            mn = fminf(mn, a);
        }
    }
    float v = (scale >= 0.f) ? mx : mn;
    out[(((size_t)n*NBR + b)*COUT + co)*(PHH*PWW) + (size_t)ph*PWW + pw] =
        fmaxf(fmaf(v, scale, shift), 0.f);
}

extern "C" void kernel_launch(void* const* d_in, const int* in_sizes, int n_in,
                              void* d_out, int out_size, void* d_ws, size_t ws_size,
                              hipStream_t stream) {
    const float* x     = (const float*)d_in[0];
    const float* w     = (const float*)d_in[1];
    const float* gamma = (const float*)d_in[2];
    const float* beta  = (const float*)d_in[3];
    float* out = (float*)d_out;

    // ws: [0,4K) stats; [4K,~209K) wt (8x64x200 bf16); [256K, +54.6MB) xpad; then y slots
    float*  stats = (float*)d_ws;
    ushort* wt    = (ushort*)((char*)d_ws + 4096);
    ushort* xp    = (ushort*)((char*)d_ws + 262144);
    const size_t ybase  = 262144 + (size_t)128*XIMG*2;   // ~54.9 MB
    const size_t yBytes = YSLOT*2;                       // 25.69 MB per branch
    ushort* y = (ushort*)((char*)d_ws + ybase);

    int ng = 0;
    if (ws_size > ybase + yBytes)
        ng = (int)((ws_size - ybase) / yBytes);
    if (ng > NBR) ng = NBR;

    if (ng >= 1) {
        hipMemsetAsync(d_ws, 0, ybase, stream);   // zeros stats + wt pad + xpad padding
        prep_w<<<(NBR*COUT*BROW + 255)/256, 256, 0, stream>>>(w, wt);
        prep_x<<<128*3*14, 256, 0, stream>>>(x, xp);
        for (int g = 0; g < NBR; g += ng) {
            int nb = (NBR - g < ng) ? (NBR - g) : ng;
            conv_mfma<<<nb*224, 256, 0, stream>>>(xp, wt, y, stats, g);
            pool_fast<<<nb*NBATCH*PHH, 256, 0, stream>>>(y, stats, gamma, beta, out, g);
        }
    } else {
        hipMemsetAsync(d_ws, 0, NBR*128*sizeof(float), stream);
        for (int b = 0; b < NBR; ++b) {
            float* statsB = stats + b*128;
            conv_bn_stats<<<NBATCH*OHH, 512, 0, stream>>>(x, w, statsB, b);
            pool_recompute<<<NBATCH*COUT*PHH*PWW/256, 256, 0, stream>>>(
                x, w, statsB, gamma + b*COUT, beta + b*COUT, out, b);
        }
    }
}